// Round 9
// baseline (143.199 us; speedup 1.0000x reference)
//
#include <hip/hip_runtime.h>
#include <hip/hip_bf16.h>

typedef __bf16 bf16_t;
typedef __bf16 bf16x8 __attribute__((ext_vector_type(8)));
typedef __bf16 bf16x4 __attribute__((ext_vector_type(4)));
typedef float f32x4 __attribute__((ext_vector_type(4)));

#define AS1 __attribute__((address_space(1)))
#define AS3 __attribute__((address_space(3)))

// ---------------------------------------------------------------------------
// fused fp32 -> bf16 conversion for all three inputs (one dispatch).
// ---------------------------------------------------------------------------
__global__ __launch_bounds__(256)
void cvt_all(const float* __restrict__ in, bf16_t* __restrict__ o_in,
             const float* __restrict__ fw, bf16_t* __restrict__ o_fw,
             const float* __restrict__ bw, bf16_t* __restrict__ o_bw) {
    int i = blockIdx.x * 256 + threadIdx.x;
    const float* s;
    bf16_t* d;
    int k;
    if (i < 786432)      { s = in; d = o_in; k = i; }
    else if (i < 811008) { s = fw; d = o_fw; k = i - 786432; }
    else if (i < 909312) { s = bw; d = o_bw; k = i - 811008; }
    else return;
    float4 a = ((const float4*)s)[k * 2];
    float4 b = ((const float4*)s)[k * 2 + 1];
    bf16x8 v;
    v[0] = (bf16_t)a.x; v[1] = (bf16_t)a.y; v[2] = (bf16_t)a.z; v[3] = (bf16_t)a.w;
    v[4] = (bf16_t)b.x; v[5] = (bf16_t)b.y; v[6] = (bf16_t)b.z; v[7] = (bf16_t)b.w;
    ((bf16x8*)d)[k] = v;
}

// ---------------------------------------------------------------------------
// gemm_bt (m97 structure) — GEMM1 only (128x64 tile, 256 blocks, 1 round).
// ---------------------------------------------------------------------------
template <int BM, int BN, int EPI>
__global__ __launch_bounds__(256)
void gemm_bt(const bf16_t* __restrict__ A, const bf16_t* __restrict__ Bm,
             void* __restrict__ Cv, const float* __restrict__ bias,
             int M, int N, int K) {
    constexpr int MR = BM / 32;
    constexpr int NR = BN / 32;
    typedef float fvec __attribute__((ext_vector_type(NR)));
    typedef bf16_t bvec __attribute__((ext_vector_type(NR)));

    __shared__ bf16_t As[BM * 64];
    __shared__ bf16_t Bs[BN * 64];

    const int tid  = threadIdx.x;
    const int lane = tid & 63;
    const int wave = tid >> 6;
    const int mblk = blockIdx.x, nblk = blockIdx.y;

    const bf16_t* Ab = A + (long)mblk * BM * K;
    const bf16_t* Bb = Bm + (long)nblk * BN * K;

    f32x4 acc[MR][NR] = {};

    const int wrow = (wave >> 1) * (BM / 2);
    const int wcol = (wave & 1) * (BN / 2);
    const int lrow = lane & 15;
    const int kgrp = lane >> 4;

    for (int k0 = 0; k0 < K; k0 += 64) {
#pragma unroll
        for (int it = 0; it < MR; ++it) {
            const int chunk = it * 256 + tid;
            const int row = chunk >> 3, c8 = chunk & 7;
            __builtin_amdgcn_global_load_lds(
                (const AS1 void*)(Ab + (long)row * K + k0 + c8 * 8),
                (AS3 void*)(As + chunk * 8), 16, 0, 0);
        }
#pragma unroll
        for (int it = 0; it < NR; ++it) {
            const int chunk = it * 256 + tid;
            const int row = chunk >> 3, c8 = chunk & 7;
            __builtin_amdgcn_global_load_lds(
                (const AS1 void*)(Bb + (long)row * K + k0 + c8 * 8),
                (AS3 void*)(Bs + chunk * 8), 16, 0, 0);
        }
        __syncthreads();

#pragma unroll
        for (int kk = 0; kk < 64; kk += 32) {
            const int koff = kk + kgrp * 8;
            bf16x8 af[MR], bfr[NR];
#pragma unroll
            for (int m = 0; m < MR; ++m)
                af[m] = *(const bf16x8*)(As + (wrow + m * 16 + lrow) * 64 + koff);
#pragma unroll
            for (int n = 0; n < NR; ++n)
                bfr[n] = *(const bf16x8*)(Bs + (wcol + lrow * NR + n) * 64 + koff);
#pragma unroll
            for (int m = 0; m < MR; ++m)
#pragma unroll
                for (int n = 0; n < NR; ++n)
                    acc[m][n] = __builtin_amdgcn_mfma_f32_16x16x32_bf16(af[m], bfr[n], acc[m][n], 0, 0, 0);
        }
        __syncthreads();
    }

    const long rbase = (long)mblk * BM + wrow + kgrp * 4;
    const long cb0   = (long)nblk * BN + wcol + lrow * NR;
    bf16_t* C = (bf16_t*)Cv;
    const float* bp = bias + cb0;
    fvec bv = *(const fvec*)bp;
#pragma unroll
    for (int m = 0; m < MR; ++m)
#pragma unroll
        for (int j = 0; j < 4; ++j) {
            bvec v;
#pragma unroll
            for (int n = 0; n < NR; ++n) v[n] = (bf16_t)(acc[m][n][j] + bv[n]);
            *(bvec*)(C + (rbase + m * 16 + j) * N + cb0) = v;
        }
}

// ---------------------------------------------------------------------------
// 8-phase 256x256 GEMM, K=256 — GEMM2 only (compute-bound, bf16 out).
// ---------------------------------------------------------------------------
template <int EPI, int XCD, int NMB, int NNB>
__global__ __launch_bounds__(512, 2)
void gemm8p(const bf16_t* __restrict__ A, const bf16_t* __restrict__ Bm,
            void* __restrict__ Cv, const float* __restrict__ bias,
            int N, long sA, long sB, long sC) {
    constexpr int K = 256;
    extern __shared__ bf16_t lds[];

    const int tid  = threadIdx.x;
    const int lane = tid & 63;
    const int wave = tid >> 6;
    const int wm = wave >> 2, wn = wave & 3;
    const int lrow = lane & 15, kgrp = lane >> 4;

    int mblk, nblk, bz;
    {
        int L = blockIdx.x;
        if (XCD) { bz = L & 7; int w = L >> 3; nblk = w % NNB; mblk = w / NNB; }
        else     { bz = 0;     mblk = L % NMB; nblk = L / NMB; }
    }

    const bf16_t* Ab = A + (long)bz * sA + (long)mblk * 256 * K;
    const bf16_t* Bb = Bm + (long)bz * sB + (long)nblk * 256 * K;

    const int c0 = tid, c1 = 512 + tid;
    const int r0 = c0 >> 3, r1 = c1 >> 3;
    const int ca0 = (c0 & 7) ^ (r0 & 7),        ca1 = (c1 & 7) ^ (r1 & 7);
    const int cb0 = (c0 & 7) ^ ((r0 >> 2) & 7), cb1 = (c1 & 7) ^ ((r1 >> 2) & 7);

    auto stageA = [&](int t, int h) {
        const bf16_t* s0 = Ab + (long)(h * 128 + r0) * K + t * 64 + ca0 * 8;
        const bf16_t* s1 = Ab + (long)(h * 128 + r1) * K + t * 64 + ca1 * 8;
        bf16_t* d = lds + ((t & 1) * 2 + h) * 8192;
        __builtin_amdgcn_global_load_lds((const AS1 void*)s0, (AS3 void*)(d + c0 * 8), 16, 0, 0);
        __builtin_amdgcn_global_load_lds((const AS1 void*)s1, (AS3 void*)(d + c1 * 8), 16, 0, 0);
    };
    auto stageB = [&](int t, int h) {
        const bf16_t* s0 = Bb + (long)(h * 128 + r0) * K + t * 64 + cb0 * 8;
        const bf16_t* s1 = Bb + (long)(h * 128 + r1) * K + t * 64 + cb1 * 8;
        bf16_t* d = lds + 32768 + ((t & 1) * 2 + h) * 8192;
        __builtin_amdgcn_global_load_lds((const AS1 void*)s0, (AS3 void*)(d + c0 * 8), 16, 0, 0);
        __builtin_amdgcn_global_load_lds((const AS1 void*)s1, (AS3 void*)(d + c1 * 8), 16, 0, 0);
    };
    auto ldA = [&](int t, int mf, int kk) -> bf16x8 {
        const int row = mf * 16 + lrow;
        const int col = (kk * 32 + kgrp * 8) ^ ((row & 7) << 3);
        return *(const bf16x8*)(lds + ((t & 1) * 2 + wm) * 8192 + row * 64 + col);
    };
    auto ldB = [&](int t, int g, int kk) -> bf16x8 {
        const int row = (wn & 1) * 64 + lrow * 4 + g;
        const int col = (kk * 32 + kgrp * 8) ^ (((row >> 2) & 7) << 3);
        return *(const bf16x8*)(lds + 32768 + ((t & 1) * 2 + (wn >> 1)) * 8192 + row * 64 + col);
    };

    f32x4 acc[8][4] = {};
    bf16x8 bfr[4][2];

    stageA(0, 0); stageA(0, 1); stageB(0, 0); stageB(0, 1); stageB(1, 0); stageB(1, 1);
    asm volatile("s_waitcnt vmcnt(4)" ::: "memory");
    __builtin_amdgcn_s_barrier();

#pragma unroll
    for (int i = 0; i < 2; ++i) {
#pragma unroll
        for (int p = 0; p < 8; ++p) {
            const int q = p & 3;
            const int t = 2 * i + (p >> 2);
            bf16x8 af[2][2];
            if (q == 0) {
#pragma unroll
                for (int g = 0; g < 4; ++g) { bfr[g][0] = ldB(t, g, 0); bfr[g][1] = ldB(t, g, 1); }
            }
#pragma unroll
            for (int mm = 0; mm < 2; ++mm) { af[mm][0] = ldA(t, 2 * q + mm, 0); af[mm][1] = ldA(t, 2 * q + mm, 1); }

            if (p == 0) stageA(2 * i + 1, 0);
            else if (p == 1) stageA(2 * i + 1, 1);
            else if (p == 2) { if (2 * i + 2 < 4) stageB(2 * i + 2, 0); }
            else if (p == 3) { if (2 * i + 2 < 4) stageB(2 * i + 2, 1); }
            else if (p == 4) { if (2 * i + 2 < 4) stageA(2 * i + 2, 0); }
            else if (p == 5) { if (2 * i + 2 < 4) stageA(2 * i + 2, 1); }
            else if (p == 6) { if (2 * i + 3 < 4) stageB(2 * i + 3, 0); }
            else             { if (2 * i + 3 < 4) stageB(2 * i + 3, 1); }

            __builtin_amdgcn_s_barrier();
            asm volatile("s_waitcnt lgkmcnt(0)" ::: "memory");
            __builtin_amdgcn_s_setprio(1);
#pragma unroll
            for (int mm = 0; mm < 2; ++mm)
#pragma unroll
                for (int g = 0; g < 4; ++g)
#pragma unroll
                    for (int kk = 0; kk < 2; ++kk)
                        acc[2 * q + mm][g] = __builtin_amdgcn_mfma_f32_16x16x32_bf16(
                            af[mm][kk], bfr[g][kk], acc[2 * q + mm][g], 0, 0, 0);
            __builtin_amdgcn_s_setprio(0);

            if (p == 3) {
                if (2 * i + 2 < 4) asm volatile("s_waitcnt vmcnt(4)" ::: "memory");
                else               asm volatile("s_waitcnt vmcnt(0)" ::: "memory");
            } else if (p == 7) {
                if (2 * i + 2 < 4) asm volatile("s_waitcnt vmcnt(4)" ::: "memory");
            }
            __builtin_amdgcn_s_barrier();
        }
    }

    const long rb = (long)mblk * 256 + wm * 128 + kgrp * 4;
    const long cb = (long)nblk * 256 + wn * 64 + lrow * 4;
    if constexpr (EPI == 0) {
        float* C = (float*)Cv + (long)bz * sC;
#pragma unroll
        for (int m = 0; m < 8; ++m)
#pragma unroll
            for (int j = 0; j < 4; ++j) {
                f32x4 v = { acc[m][0][j], acc[m][1][j], acc[m][2][j], acc[m][3][j] };
                __builtin_nontemporal_store(v, (f32x4*)(C + (rb + m * 16 + j) * N + cb));
            }
    } else {
        bf16_t* C = (bf16_t*)Cv;
        f32x4 bv = *(const f32x4*)(bias + (int)(cb & 255));
#pragma unroll
        for (int m = 0; m < 8; ++m)
#pragma unroll
            for (int j = 0; j < 4; ++j) {
                bf16x4 v;
#pragma unroll
                for (int g = 0; g < 4; ++g) v[g] = (bf16_t)(acc[m][g][j] + bv[g]);
                *(bf16x4*)(C + (rb + m * 16 + j) * N + cb) = v;
            }
    }
}

// ---------------------------------------------------------------------------
// GEMM3 persistent + continuous NT stores: out_b = bl_b @ t_b^T, WRITE-BOUND.
// Block owns a 96-row A-panel (staged once, 48 KB), walks 8 nblk; B 64-K
// chunks double-buffered (2x16 KB). LDS 80 KB -> 2 blocks/CU; 1024 blocks.
// Double accumulator aE/aO (fully unrolled, static idx): tile nb's 12 NT
// stores issue 3-per-step DURING tile nb+1 -> write pipe continuously fed.
// Sync per step s (nb=s>>2, t=s&3):
//   vmcnt(T)  T = exact #ops newer than stageB(s) = 3 stores (0 for s<=4)
//             -> stageB(s) landed; store queue never force-drained below 3
//   s_barrier -> all waves' stageB(s) landed, all reads(s-1) done
//   stageB(s+1) [safe: buf last read at s-1]
//   ds_read(s); lgkmcnt(0); 24 MFMA into cur; 3 stores of prv
// Addressing identical to gemm3p (refcheck'd). Tail: store tile 7 after loop.
// ---------------------------------------------------------------------------
__global__ __launch_bounds__(256, 2)
void gemm3q(const bf16_t* __restrict__ A, const bf16_t* __restrict__ Bm,
            float* __restrict__ C, long sA, long sB, long sC) {
    extern __shared__ bf16_t lds[];
    bf16_t* Alds = lds;           // 96*256 elems (48 KB)
    bf16_t* Blds = lds + 24576;   // 2 x 8192 elems (32 KB)

    const int tid  = threadIdx.x;
    const int lane = tid & 63;
    const int wave = tid >> 6;
    const int wm = wave >> 1, wn = wave & 1;
    const int lrow = lane & 15, kgrp = lane >> 4;

    const int L = blockIdx.x;
    const int bz = L & 7;
    const int mblk = L >> 3;

    const bf16_t* Ab = A + (long)bz * sA + (long)mblk * 96 * 256;
    const bf16_t* Bb = Bm + (long)bz * sB;

    auto stageB = [&](int s) {   // s: nb=s>>2, kchunk=s&3, buf=s&1
        const bf16_t* base = Bb + (long)(s >> 2) * 128 * 256;
#pragma unroll
        for (int it = 0; it < 4; ++it) {
            const int c = it * 256 + tid, row = c >> 3;
            const int sb = (c & 7) ^ ((row >> 2) & 7);
            __builtin_amdgcn_global_load_lds(
                (const AS1 void*)(base + (long)row * 256 + (s & 3) * 64 + sb * 8),
                (AS3 void*)(Blds + (s & 1) * 8192 + c * 8), 16, 0, 0);
        }
    };

    // prologue: A panel + B(0); single drain.
#pragma unroll
    for (int it = 0; it < 12; ++it) {
        const int c = it * 256 + tid;
        const int row = c >> 5;
        const int s8 = (c & 31) ^ (row & 7);
        __builtin_amdgcn_global_load_lds(
            (const AS1 void*)(Ab + (long)row * 256 + s8 * 8),
            (AS3 void*)(Alds + c * 8), 16, 0, 0);
    }
    stageB(0);
    asm volatile("s_waitcnt vmcnt(0)" ::: "memory");
    __builtin_amdgcn_s_barrier();

    f32x4 aE[3][4] = {}, aO[3][4] = {};
    float* Cb = C + (long)bz * sC;
    const long rb = (long)mblk * 96 + wm * 48 + kgrp * 4;
    const int cbl = wn * 64 + lrow * 4;

    auto tile = [&](int nb, f32x4 (&cur)[3][4], f32x4 (&prv)[3][4]) {
#pragma unroll
        for (int t = 0; t < 4; ++t) {
            const int s = nb * 4 + t;
            // (c) counted wait for own stageB(s); never force-drains stores
            if (s <= 4) asm volatile("s_waitcnt vmcnt(0)" ::: "memory");
            else        asm volatile("s_waitcnt vmcnt(3)" ::: "memory");
            // (d) publish: all waves' stageB(s) landed; reads(s-1) done
            __builtin_amdgcn_s_barrier();
            // (e) prefetch next chunk
            if (s < 31) stageB(s + 1);
            // (f) fragments + MFMA
            bf16x8 af[3][2], bfr[4][2];
#pragma unroll
            for (int m = 0; m < 3; ++m) {
                const int r = wm * 48 + m * 16 + lrow;
#pragma unroll
                for (int kk = 0; kk < 2; ++kk) {
                    const int g8 = t * 8 + kk * 4 + kgrp;
                    af[m][kk] = *(const bf16x8*)(Alds + r * 256 + (g8 ^ (r & 7)) * 8);
                }
            }
#pragma unroll
            for (int g = 0; g < 4; ++g) {
                const int r = wn * 64 + lrow * 4 + g;
#pragma unroll
                for (int kk = 0; kk < 2; ++kk)
                    bfr[g][kk] = *(const bf16x8*)(Blds + (s & 1) * 8192 + r * 64 +
                                                  ((kk * 32 + kgrp * 8) ^ (((r >> 2) & 7) << 3)));
            }
            asm volatile("s_waitcnt lgkmcnt(0)" ::: "memory");
            __builtin_amdgcn_s_setprio(1);
#pragma unroll
            for (int m = 0; m < 3; ++m)
#pragma unroll
                for (int g = 0; g < 4; ++g)
#pragma unroll
                    for (int kk = 0; kk < 2; ++kk)
                        cur[m][g] = __builtin_amdgcn_mfma_f32_16x16x32_bf16(
                            af[m][kk], bfr[g][kk], cur[m][g], 0, 0, 0);
            __builtin_amdgcn_s_setprio(0);
            // (g) 3 NT stores of PREVIOUS tile (spread across the 4 steps)
            if (nb >= 1) {
                const long cbP = (long)(nb - 1) * 128 + cbl;
#pragma unroll
                for (int k = 0; k < 3; ++k) {
                    const int idx = t * 3 + k, m = idx >> 2, j = idx & 3;
                    f32x4 v = { prv[m][0][j], prv[m][1][j], prv[m][2][j], prv[m][3][j] };
                    __builtin_nontemporal_store(v, (f32x4*)(Cb + (rb + m * 16 + j) * 1024 + cbP));
                }
                if (t == 3) {
#pragma unroll
                    for (int m = 0; m < 3; ++m)
#pragma unroll
                        for (int g = 0; g < 4; ++g)
                            prv[m][g] = f32x4{0.f, 0.f, 0.f, 0.f};
                }
            }
        }
    };

#pragma unroll
    for (int nb = 0; nb < 8; ++nb) {
        if ((nb & 1) == 0) tile(nb, aE, aO);
        else               tile(nb, aO, aE);
    }

    // tail: tile 7 (in aO) stored directly; drained at s_endpgm.
    {
        const long cbP = 7L * 128 + cbl;
#pragma unroll
        for (int m = 0; m < 3; ++m)
#pragma unroll
            for (int j = 0; j < 4; ++j) {
                f32x4 v = { aO[m][0][j], aO[m][1][j], aO[m][2][j], aO[m][3][j] };
                __builtin_nontemporal_store(v, (f32x4*)(Cb + (rb + m * 16 + j) * 1024 + cbP));
            }
    }
}

// ---------------------------------------------------------------------------
// B=8, S=1024, IN=768, E=256, L=12
// ---------------------------------------------------------------------------
extern "C" void kernel_launch(void* const* d_in, const int* in_sizes, int n_in,
                              void* d_out, int out_size, void* d_ws, size_t ws_size,
                              hipStream_t stream) {
    const float* input = (const float*)d_in[0];
    const float* fc_w  = (const float*)d_in[1];
    const float* fc_b  = (const float*)d_in[2];
    const float* bi_w  = (const float*)d_in[3];
    const float* bias  = (const float*)d_in[4];

    char* ws = (char*)d_ws;
    bf16_t* inA = (bf16_t*)(ws);             // 8192*768*2
    bf16_t* wfc = (bf16_t*)(ws + 12582912);  // 256*768*2
    bf16_t* wbi = (bf16_t*)(ws + 12976128);  // 3072*256*2
    bf16_t* t   = (bf16_t*)(ws + 14548992);  // 8192*256*2
    bf16_t* bl  = (bf16_t*)(ws + 18743296);  // 8192*3072*2

    cvt_all<<<dim3(3552), dim3(256), 0, stream>>>(input, inA, fc_w, wfc, bi_w, wbi);

    // GEMM1: t = inA @ wfc^T + fc_b   (K=768; 128x64 tile -> 256 blocks)
    gemm_bt<128, 64, 1><<<dim3(64, 4), dim3(256), 0, stream>>>(
        inA, wfc, (void*)t, fc_b, 8192, 256, 768);

    // GEMM2: bl = t @ wbi^T + bias[col&255]  (8-phase 256^2; 384 blocks)
    gemm8p<2, 0, 32, 12><<<dim3(384), dim3(512), 131072, stream>>>(
        t, wbi, (void*)bl, bias, 3072, 0L, 0L, 0L);

    // GEMM3 (batched x8): persistent panel + continuous NT store stream
    // 128 mblk x 8 bz = 1024 blocks, 2/CU, 2 rounds
    gemm3q<<<dim3(1024), dim3(256), 81920, stream>>>(
        bl, t, (float*)d_out,
        (long)12288 * 256, (long)1024 * 256, (long)12288 * 1024);
}

// Round 10
// 127.313 us; speedup vs baseline: 1.1248x; 1.1248x over previous
//
#include <hip/hip_runtime.h>
#include <hip/hip_bf16.h>

typedef __bf16 bf16_t;
typedef __bf16 bf16x8 __attribute__((ext_vector_type(8)));
typedef __bf16 bf16x4 __attribute__((ext_vector_type(4)));
typedef float f32x4 __attribute__((ext_vector_type(4)));

#define AS1 __attribute__((address_space(1)))
#define AS3 __attribute__((address_space(3)))

// ---------------------------------------------------------------------------
// fp32 -> bf16 conversion, WEIGHTS ONLY (fc_w 24576 + bi_w 98304 chunks).
// Input conversion is fused into GEMM1's A-staging.
// ---------------------------------------------------------------------------
__global__ __launch_bounds__(256)
void cvt_w(const float* __restrict__ fw, bf16_t* __restrict__ o_fw,
           const float* __restrict__ bw, bf16_t* __restrict__ o_bw) {
    int i = blockIdx.x * 256 + threadIdx.x;
    const float* s;
    bf16_t* d;
    int k;
    if (i < 24576)       { s = fw; d = o_fw; k = i; }
    else if (i < 122880) { s = bw; d = o_bw; k = i - 24576; }
    else return;
    float4 a = ((const float4*)s)[k * 2];
    float4 b = ((const float4*)s)[k * 2 + 1];
    bf16x8 v;
    v[0] = (bf16_t)a.x; v[1] = (bf16_t)a.y; v[2] = (bf16_t)a.z; v[3] = (bf16_t)a.w;
    v[4] = (bf16_t)b.x; v[5] = (bf16_t)b.y; v[6] = (bf16_t)b.z; v[7] = (bf16_t)b.w;
    ((bf16x8*)d)[k] = v;
}

// ---------------------------------------------------------------------------
// GEMM1 with fused fp32->bf16 on A: t = input_f32 @ wfc_bf16^T + fc_b.
// 128x64 tile, m97 2-phase structure. A staged via reg (float4 -> cvt ->
// ds_write_b64); B staged via global_load_lds. Saves the 25 MB input
// cvt round-trip (12.6 MB write + 12.6 MB re-read) and most of the cvt
// dispatch.
// ---------------------------------------------------------------------------
__global__ __launch_bounds__(256)
void gemm1f(const float* __restrict__ Af, const bf16_t* __restrict__ Bm,
            bf16_t* __restrict__ C, const float* __restrict__ bias,
            int M, int N, int K) {
    constexpr int BM = 128, BN = 64;
    constexpr int MR = 4, NR = 2;    // BM/32, BN/32
    typedef float fvec __attribute__((ext_vector_type(NR)));
    typedef bf16_t bvec __attribute__((ext_vector_type(NR)));

    __shared__ bf16_t As[BM * 64];
    __shared__ bf16_t Bs[BN * 64];

    const int tid  = threadIdx.x;
    const int lane = tid & 63;
    const int wave = tid >> 6;
    const int mblk = blockIdx.x, nblk = blockIdx.y;

    const float*  Ab = Af + (long)mblk * BM * K;
    const bf16_t* Bb = Bm + (long)nblk * BN * K;

    f32x4 acc[MR][NR] = {};

    const int wrow = (wave >> 1) * (BM / 2);
    const int wcol = (wave & 1) * (BN / 2);
    const int lrow = lane & 15;
    const int kgrp = lane >> 4;

    for (int k0 = 0; k0 < K; k0 += 64) {
        // A: 128x64 fp32 -> bf16. 2048 4-elem chunks, 8 per thread.
#pragma unroll
        for (int it = 0; it < 8; ++it) {
            const int c = it * 256 + tid;
            const int row = c >> 4, c4 = c & 15;
            f32x4 v = *(const f32x4*)(Ab + (long)row * K + k0 + c4 * 4);
            bf16x4 w = { (bf16_t)v[0], (bf16_t)v[1], (bf16_t)v[2], (bf16_t)v[3] };
            *(bf16x4*)(As + row * 64 + c4 * 4) = w;
        }
        // B: 64x64 bf16 via global_load_lds (512 chunks, 2 per thread).
#pragma unroll
        for (int it = 0; it < NR; ++it) {
            const int chunk = it * 256 + tid;
            const int row = chunk >> 3, c8 = chunk & 7;
            __builtin_amdgcn_global_load_lds(
                (const AS1 void*)(Bb + (long)row * K + k0 + c8 * 8),
                (AS3 void*)(Bs + chunk * 8), 16, 0, 0);
        }
        __syncthreads();

#pragma unroll
        for (int kk = 0; kk < 64; kk += 32) {
            const int koff = kk + kgrp * 8;
            bf16x8 af[MR], bfr[NR];
#pragma unroll
            for (int m = 0; m < MR; ++m)
                af[m] = *(const bf16x8*)(As + (wrow + m * 16 + lrow) * 64 + koff);
#pragma unroll
            for (int n = 0; n < NR; ++n)
                bfr[n] = *(const bf16x8*)(Bs + (wcol + lrow * NR + n) * 64 + koff);
#pragma unroll
            for (int m = 0; m < MR; ++m)
#pragma unroll
                for (int n = 0; n < NR; ++n)
                    acc[m][n] = __builtin_amdgcn_mfma_f32_16x16x32_bf16(af[m], bfr[n], acc[m][n], 0, 0, 0);
        }
        __syncthreads();
    }

    const long rbase = (long)mblk * BM + wrow + kgrp * 4;
    const long cb0   = (long)nblk * BN + wcol + lrow * NR;
    const float* bp = bias + cb0;
    fvec bv = *(const fvec*)bp;
#pragma unroll
    for (int m = 0; m < MR; ++m)
#pragma unroll
        for (int j = 0; j < 4; ++j) {
            bvec v;
#pragma unroll
            for (int n = 0; n < NR; ++n) v[n] = (bf16_t)(acc[m][n][j] + bv[n]);
            *(bvec*)(C + (rbase + m * 16 + j) * N + cb0) = v;
        }
}

// ---------------------------------------------------------------------------
// 8-phase 256x256 GEMM, K=256 — GEMM2 only (compute-bound, bf16 out).
// ---------------------------------------------------------------------------
template <int EPI, int XCD, int NMB, int NNB>
__global__ __launch_bounds__(512, 2)
void gemm8p(const bf16_t* __restrict__ A, const bf16_t* __restrict__ Bm,
            void* __restrict__ Cv, const float* __restrict__ bias,
            int N, long sA, long sB, long sC) {
    constexpr int K = 256;
    extern __shared__ bf16_t lds[];

    const int tid  = threadIdx.x;
    const int lane = tid & 63;
    const int wave = tid >> 6;
    const int wm = wave >> 2, wn = wave & 3;
    const int lrow = lane & 15, kgrp = lane >> 4;

    int mblk, nblk, bz;
    {
        int L = blockIdx.x;
        if (XCD) { bz = L & 7; int w = L >> 3; nblk = w % NNB; mblk = w / NNB; }
        else     { bz = 0;     mblk = L % NMB; nblk = L / NMB; }
    }

    const bf16_t* Ab = A + (long)bz * sA + (long)mblk * 256 * K;
    const bf16_t* Bb = Bm + (long)bz * sB + (long)nblk * 256 * K;

    const int c0 = tid, c1 = 512 + tid;
    const int r0 = c0 >> 3, r1 = c1 >> 3;
    const int ca0 = (c0 & 7) ^ (r0 & 7),        ca1 = (c1 & 7) ^ (r1 & 7);
    const int cb0 = (c0 & 7) ^ ((r0 >> 2) & 7), cb1 = (c1 & 7) ^ ((r1 >> 2) & 7);

    auto stageA = [&](int t, int h) {
        const bf16_t* s0 = Ab + (long)(h * 128 + r0) * K + t * 64 + ca0 * 8;
        const bf16_t* s1 = Ab + (long)(h * 128 + r1) * K + t * 64 + ca1 * 8;
        bf16_t* d = lds + ((t & 1) * 2 + h) * 8192;
        __builtin_amdgcn_global_load_lds((const AS1 void*)s0, (AS3 void*)(d + c0 * 8), 16, 0, 0);
        __builtin_amdgcn_global_load_lds((const AS1 void*)s1, (AS3 void*)(d + c1 * 8), 16, 0, 0);
    };
    auto stageB = [&](int t, int h) {
        const bf16_t* s0 = Bb + (long)(h * 128 + r0) * K + t * 64 + cb0 * 8;
        const bf16_t* s1 = Bb + (long)(h * 128 + r1) * K + t * 64 + cb1 * 8;
        bf16_t* d = lds + 32768 + ((t & 1) * 2 + h) * 8192;
        __builtin_amdgcn_global_load_lds((const AS1 void*)s0, (AS3 void*)(d + c0 * 8), 16, 0, 0);
        __builtin_amdgcn_global_load_lds((const AS1 void*)s1, (AS3 void*)(d + c1 * 8), 16, 0, 0);
    };
    auto ldA = [&](int t, int mf, int kk) -> bf16x8 {
        const int row = mf * 16 + lrow;
        const int col = (kk * 32 + kgrp * 8) ^ ((row & 7) << 3);
        return *(const bf16x8*)(lds + ((t & 1) * 2 + wm) * 8192 + row * 64 + col);
    };
    auto ldB = [&](int t, int g, int kk) -> bf16x8 {
        const int row = (wn & 1) * 64 + lrow * 4 + g;
        const int col = (kk * 32 + kgrp * 8) ^ (((row >> 2) & 7) << 3);
        return *(const bf16x8*)(lds + 32768 + ((t & 1) * 2 + (wn >> 1)) * 8192 + row * 64 + col);
    };

    f32x4 acc[8][4] = {};
    bf16x8 bfr[4][2];

    stageA(0, 0); stageA(0, 1); stageB(0, 0); stageB(0, 1); stageB(1, 0); stageB(1, 1);
    asm volatile("s_waitcnt vmcnt(4)" ::: "memory");
    __builtin_amdgcn_s_barrier();

#pragma unroll
    for (int i = 0; i < 2; ++i) {
#pragma unroll
        for (int p = 0; p < 8; ++p) {
            const int q = p & 3;
            const int t = 2 * i + (p >> 2);
            bf16x8 af[2][2];
            if (q == 0) {
#pragma unroll
                for (int g = 0; g < 4; ++g) { bfr[g][0] = ldB(t, g, 0); bfr[g][1] = ldB(t, g, 1); }
            }
#pragma unroll
            for (int mm = 0; mm < 2; ++mm) { af[mm][0] = ldA(t, 2 * q + mm, 0); af[mm][1] = ldA(t, 2 * q + mm, 1); }

            if (p == 0) stageA(2 * i + 1, 0);
            else if (p == 1) stageA(2 * i + 1, 1);
            else if (p == 2) { if (2 * i + 2 < 4) stageB(2 * i + 2, 0); }
            else if (p == 3) { if (2 * i + 2 < 4) stageB(2 * i + 2, 1); }
            else if (p == 4) { if (2 * i + 2 < 4) stageA(2 * i + 2, 0); }
            else if (p == 5) { if (2 * i + 2 < 4) stageA(2 * i + 2, 1); }
            else if (p == 6) { if (2 * i + 3 < 4) stageB(2 * i + 3, 0); }
            else             { if (2 * i + 3 < 4) stageB(2 * i + 3, 1); }

            __builtin_amdgcn_s_barrier();
            asm volatile("s_waitcnt lgkmcnt(0)" ::: "memory");
            __builtin_amdgcn_s_setprio(1);
#pragma unroll
            for (int mm = 0; mm < 2; ++mm)
#pragma unroll
                for (int g = 0; g < 4; ++g)
#pragma unroll
                    for (int kk = 0; kk < 2; ++kk)
                        acc[2 * q + mm][g] = __builtin_amdgcn_mfma_f32_16x16x32_bf16(
                            af[mm][kk], bfr[g][kk], acc[2 * q + mm][g], 0, 0, 0);
            __builtin_amdgcn_s_setprio(0);

            if (p == 3) {
                if (2 * i + 2 < 4) asm volatile("s_waitcnt vmcnt(4)" ::: "memory");
                else               asm volatile("s_waitcnt vmcnt(0)" ::: "memory");
            } else if (p == 7) {
                if (2 * i + 2 < 4) asm volatile("s_waitcnt vmcnt(4)" ::: "memory");
            }
            __builtin_amdgcn_s_barrier();
        }
    }

    const long rb = (long)mblk * 256 + wm * 128 + kgrp * 4;
    const long cb = (long)nblk * 256 + wn * 64 + lrow * 4;
    if constexpr (EPI == 0) {
        float* C = (float*)Cv + (long)bz * sC;
#pragma unroll
        for (int m = 0; m < 8; ++m)
#pragma unroll
            for (int j = 0; j < 4; ++j) {
                f32x4 v = { acc[m][0][j], acc[m][1][j], acc[m][2][j], acc[m][3][j] };
                __builtin_nontemporal_store(v, (f32x4*)(C + (rb + m * 16 + j) * N + cb));
            }
    } else {
        bf16_t* C = (bf16_t*)Cv;
        f32x4 bv = *(const f32x4*)(bias + (int)(cb & 255));
#pragma unroll
        for (int m = 0; m < 8; ++m)
#pragma unroll
            for (int j = 0; j < 4; ++j) {
                bf16x4 v;
#pragma unroll
                for (int g = 0; g < 4; ++g) v[g] = (bf16_t)(acc[m][g][j] + bv[g]);
                *(bf16x4*)(C + (rb + m * 16 + j) * N + cb) = v;
            }
    }
}

// ---------------------------------------------------------------------------
// GEMM3 (R6 form — best measured): out_b = bl_b[12288,256] @ t_b[1024,256]^T,
// fp32 NT out. 192x128 tile, BK=64 dbuf, 256 threads, 80 KB LDS -> 2
// blocks/CU; stage(t+1) -> ds_read(t) -> 48 MFMA -> __syncthreads.
// ---------------------------------------------------------------------------
template <int NNB>
__global__ __launch_bounds__(256, 2)
void gemm3k(const bf16_t* __restrict__ A, const bf16_t* __restrict__ Bm,
            float* __restrict__ C, long sA, long sB, long sC) {
    constexpr int K = 256, BM = 192, BN = 128;
    extern __shared__ bf16_t lds[];   // A: buf*12288 ; B: 24576 + buf*8192

    const int tid  = threadIdx.x;
    const int lane = tid & 63;
    const int wave = tid >> 6;
    const int wm = wave >> 1, wn = wave & 1;
    const int lrow = lane & 15, kgrp = lane >> 4;

    const int L = blockIdx.x;
    const int bz = L & 7;
    const int w = L >> 3;
    const int nblk = w & (NNB - 1), mblk = w / NNB;

    const bf16_t* Ab = A + (long)bz * sA + (long)mblk * BM * K;
    const bf16_t* Bb = Bm + (long)bz * sB + (long)nblk * BN * K;

    auto stage = [&](int t) {
        const int buf = t & 1;
#pragma unroll
        for (int it = 0; it < 6; ++it) {          // A: 192x64 = 1536 chunks
            const int c = it * 256 + tid, row = c >> 3;
            const int sa = (c & 7) ^ (row & 7);
            __builtin_amdgcn_global_load_lds(
                (const AS1 void*)(Ab + (long)row * K + t * 64 + sa * 8),
                (AS3 void*)(lds + buf * 12288 + c * 8), 16, 0, 0);
        }
#pragma unroll
        for (int it = 0; it < 4; ++it) {          // B: 128x64 = 1024 chunks
            const int c = it * 256 + tid, row = c >> 3;
            const int sb = (c & 7) ^ ((row >> 2) & 7);
            __builtin_amdgcn_global_load_lds(
                (const AS1 void*)(Bb + (long)row * K + t * 64 + sb * 8),
                (AS3 void*)(lds + 24576 + buf * 8192 + c * 8), 16, 0, 0);
        }
    };

    f32x4 acc[6][4] = {};

    stage(0);
    __syncthreads();

#pragma unroll
    for (int t = 0; t < 4; ++t) {
        if (t < 3) stage(t + 1);
        const int buf = t & 1;
        bf16x8 af[6][2], bfr[4][2];
#pragma unroll
        for (int m = 0; m < 6; ++m) {
            const int r = wm * 96 + m * 16 + lrow;
#pragma unroll
            for (int kk = 0; kk < 2; ++kk)
                af[m][kk] = *(const bf16x8*)(lds + buf * 12288 + r * 64 +
                                             ((kk * 32 + kgrp * 8) ^ ((r & 7) << 3)));
        }
#pragma unroll
        for (int g = 0; g < 4; ++g) {
            const int r = wn * 64 + lrow * 4 + g;
#pragma unroll
            for (int kk = 0; kk < 2; ++kk)
                bfr[g][kk] = *(const bf16x8*)(lds + 24576 + buf * 8192 + r * 64 +
                                              ((kk * 32 + kgrp * 8) ^ (((r >> 2) & 7) << 3)));
        }
        __builtin_amdgcn_s_setprio(1);
#pragma unroll
        for (int m = 0; m < 6; ++m)
#pragma unroll
            for (int g = 0; g < 4; ++g)
#pragma unroll
                for (int kk = 0; kk < 2; ++kk)
                    acc[m][g] = __builtin_amdgcn_mfma_f32_16x16x32_bf16(
                        af[m][kk], bfr[g][kk], acc[m][g], 0, 0, 0);
        __builtin_amdgcn_s_setprio(0);
        __syncthreads();
    }

    float* Cb = C + (long)bz * sC;
    const long rb = (long)mblk * BM + wm * 96 + kgrp * 4;
    const long cb = (long)nblk * BN + wn * 64 + lrow * 4;
#pragma unroll
    for (int m = 0; m < 6; ++m)
#pragma unroll
        for (int j = 0; j < 4; ++j) {
            f32x4 v = { acc[m][0][j], acc[m][1][j], acc[m][2][j], acc[m][3][j] };
            __builtin_nontemporal_store(v, (f32x4*)(Cb + (rb + m * 16 + j) * 1024 + cb));
        }
}

// ---------------------------------------------------------------------------
// B=8, S=1024, IN=768, E=256, L=12
// ---------------------------------------------------------------------------
extern "C" void kernel_launch(void* const* d_in, const int* in_sizes, int n_in,
                              void* d_out, int out_size, void* d_ws, size_t ws_size,
                              hipStream_t stream) {
    const float* input = (const float*)d_in[0];
    const float* fc_w  = (const float*)d_in[1];
    const float* fc_b  = (const float*)d_in[2];
    const float* bi_w  = (const float*)d_in[3];
    const float* bias  = (const float*)d_in[4];

    char* ws = (char*)d_ws;
    bf16_t* wfc = (bf16_t*)(ws);             // 256*768*2  =   393,216
    bf16_t* wbi = (bf16_t*)(ws + 393216);    // 3072*256*2 = 1,572,864
    bf16_t* t   = (bf16_t*)(ws + 1966080);   // 8192*256*2 = 4,194,304
    bf16_t* bl  = (bf16_t*)(ws + 6160384);   // 8192*3072*2 = 50,331,648

    // weights-only cvt (122880 chunks -> 480 blocks)
    cvt_w<<<dim3(480), dim3(256), 0, stream>>>(fc_w, wfc, bi_w, wbi);

    // GEMM1 (fused fp32 A conversion): t = input @ wfc^T + fc_b
    gemm1f<<<dim3(64, 4), dim3(256), 0, stream>>>(
        input, wfc, t, fc_b, 8192, 256, 768);

    // GEMM2: bl = t @ wbi^T + bias[col&255]  (8-phase 256^2; 384 blocks)
    gemm8p<2, 0, 32, 12><<<dim3(384), dim3(512), 131072, stream>>>(
        t, wbi, (void*)bl, bias, 3072, 0L, 0L, 0L);

    // GEMM3 (batched x8): 192x128 tile, 4096 blocks, 2/CU, NT stores
    gemm3k<8><<<dim3(4096), dim3(256), 81920, stream>>>(
        bl, t, (float*)d_out,
        (long)12288 * 256, (long)1024 * 256, (long)12288 * 1024);
}

// Round 11
// 123.064 us; speedup vs baseline: 1.1636x; 1.0345x over previous
//
#include <hip/hip_runtime.h>
#include <hip/hip_bf16.h>

typedef __bf16 bf16_t;
typedef __bf16 bf16x8 __attribute__((ext_vector_type(8)));
typedef __bf16 bf16x4 __attribute__((ext_vector_type(4)));
typedef float f32x4 __attribute__((ext_vector_type(4)));

#define AS1 __attribute__((address_space(1)))
#define AS3 __attribute__((address_space(3)))

// ---------------------------------------------------------------------------
// Fused front-end, ONE dispatch (640 blocks x 256):
//   blocks 0..383   : bi_w fp32->bf16 (98304 chunks, exactly 1/thread)
//   blocks 384..639 : GEMM1  t = input_f32 @ fc_w_f32^T + fc_b  (bf16 out)
//                     A and B both converted fp32->bf16 during staging
//                     (reg-stage: float4 -> cvt -> ds_write); no wfc buffer.
// ---------------------------------------------------------------------------
__global__ __launch_bounds__(256)
void frontend(const float* __restrict__ input, const float* __restrict__ fc_w,
              const float* __restrict__ fc_b, const float* __restrict__ bi_w,
              bf16_t* __restrict__ o_bw, bf16_t* __restrict__ t_out) {
    const int bid = blockIdx.x;
    const int tid = threadIdx.x;

    if (bid < 384) {
        // ---- bi_w conversion: chunk k = bid*256+tid of 98304 ----
        const int k = bid * 256 + tid;
        float4 a = ((const float4*)bi_w)[k * 2];
        float4 b = ((const float4*)bi_w)[k * 2 + 1];
        bf16x8 v;
        v[0] = (bf16_t)a.x; v[1] = (bf16_t)a.y; v[2] = (bf16_t)a.z; v[3] = (bf16_t)a.w;
        v[4] = (bf16_t)b.x; v[5] = (bf16_t)b.y; v[6] = (bf16_t)b.z; v[7] = (bf16_t)b.w;
        ((bf16x8*)o_bw)[k] = v;
        return;
    }

    // ---- GEMM1: 128x64 tile, m97 2-phase; g = 0..255 -> mblk 0..63, nblk 0..3
    constexpr int K = 768, N = 256;
    constexpr int MR = 4, NR = 2;
    __shared__ bf16_t As[128 * 64];
    __shared__ bf16_t Bs[64 * 64];

    const int g = bid - 384;
    const int mblk = g & 63, nblk = g >> 6;
    const int lane = tid & 63;
    const int wave = tid >> 6;

    const float* Ab = input + (long)mblk * 128 * K;
    const float* Bf = fc_w + (long)nblk * 64 * K;

    f32x4 acc[MR][NR] = {};

    const int wrow = (wave >> 1) * 64;
    const int wcol = (wave & 1) * 32;
    const int lrow = lane & 15;
    const int kgrp = lane >> 4;

    for (int k0 = 0; k0 < K; k0 += 64) {
        // A: 128x64 fp32 -> bf16 (2048 4-elem chunks, 8/thread)
#pragma unroll
        for (int it = 0; it < 8; ++it) {
            const int c = it * 256 + tid;
            const int row = c >> 4, c4 = c & 15;
            f32x4 v = *(const f32x4*)(Ab + (long)row * K + k0 + c4 * 4);
            bf16x4 w = { (bf16_t)v[0], (bf16_t)v[1], (bf16_t)v[2], (bf16_t)v[3] };
            *(bf16x4*)(As + row * 64 + c4 * 4) = w;
        }
        // B: 64x64 fp32 -> bf16 (1024 chunks, 4/thread)
#pragma unroll
        for (int it = 0; it < 4; ++it) {
            const int c = it * 256 + tid;
            const int row = c >> 4, c4 = c & 15;
            f32x4 v = *(const f32x4*)(Bf + (long)row * K + k0 + c4 * 4);
            bf16x4 w = { (bf16_t)v[0], (bf16_t)v[1], (bf16_t)v[2], (bf16_t)v[3] };
            *(bf16x4*)(Bs + row * 64 + c4 * 4) = w;
        }
        __syncthreads();

#pragma unroll
        for (int kk = 0; kk < 64; kk += 32) {
            const int koff = kk + kgrp * 8;
            bf16x8 af[MR], bfr[NR];
#pragma unroll
            for (int m = 0; m < MR; ++m)
                af[m] = *(const bf16x8*)(As + (wrow + m * 16 + lrow) * 64 + koff);
#pragma unroll
            for (int n = 0; n < NR; ++n)
                bfr[n] = *(const bf16x8*)(Bs + (wcol + lrow * NR + n) * 64 + koff);
#pragma unroll
            for (int m = 0; m < MR; ++m)
#pragma unroll
                for (int n = 0; n < NR; ++n)
                    acc[m][n] = __builtin_amdgcn_mfma_f32_16x16x32_bf16(af[m], bfr[n], acc[m][n], 0, 0, 0);
        }
        __syncthreads();
    }

    typedef float fvec __attribute__((ext_vector_type(NR)));
    typedef bf16_t bvec __attribute__((ext_vector_type(NR)));
    const long rbase = (long)mblk * 128 + wrow + kgrp * 4;
    const long cb0   = (long)nblk * 64 + wcol + lrow * NR;
    fvec bv = *(const fvec*)(fc_b + cb0);
#pragma unroll
    for (int m = 0; m < MR; ++m)
#pragma unroll
        for (int j = 0; j < 4; ++j) {
            bvec v;
#pragma unroll
            for (int n = 0; n < NR; ++n) v[n] = (bf16_t)(acc[m][n][j] + bv[n]);
            *(bvec*)(t_out + (rbase + m * 16 + j) * N + cb0) = v;
        }
}

// ---------------------------------------------------------------------------
// 8-phase 256x256 GEMM, K=256 — GEMM2 only (compute-bound, bf16 out).
// ---------------------------------------------------------------------------
template <int EPI, int XCD, int NMB, int NNB>
__global__ __launch_bounds__(512, 2)
void gemm8p(const bf16_t* __restrict__ A, const bf16_t* __restrict__ Bm,
            void* __restrict__ Cv, const float* __restrict__ bias,
            int N, long sA, long sB, long sC) {
    constexpr int K = 256;
    extern __shared__ bf16_t lds[];

    const int tid  = threadIdx.x;
    const int lane = tid & 63;
    const int wave = tid >> 6;
    const int wm = wave >> 2, wn = wave & 3;
    const int lrow = lane & 15, kgrp = lane >> 4;

    int mblk, nblk, bz;
    {
        int L = blockIdx.x;
        if (XCD) { bz = L & 7; int w = L >> 3; nblk = w % NNB; mblk = w / NNB; }
        else     { bz = 0;     mblk = L % NMB; nblk = L / NMB; }
    }

    const bf16_t* Ab = A + (long)bz * sA + (long)mblk * 256 * K;
    const bf16_t* Bb = Bm + (long)bz * sB + (long)nblk * 256 * K;

    const int c0 = tid, c1 = 512 + tid;
    const int r0 = c0 >> 3, r1 = c1 >> 3;
    const int ca0 = (c0 & 7) ^ (r0 & 7),        ca1 = (c1 & 7) ^ (r1 & 7);
    const int cb0 = (c0 & 7) ^ ((r0 >> 2) & 7), cb1 = (c1 & 7) ^ ((r1 >> 2) & 7);

    auto stageA = [&](int t, int h) {
        const bf16_t* s0 = Ab + (long)(h * 128 + r0) * K + t * 64 + ca0 * 8;
        const bf16_t* s1 = Ab + (long)(h * 128 + r1) * K + t * 64 + ca1 * 8;
        bf16_t* d = lds + ((t & 1) * 2 + h) * 8192;
        __builtin_amdgcn_global_load_lds((const AS1 void*)s0, (AS3 void*)(d + c0 * 8), 16, 0, 0);
        __builtin_amdgcn_global_load_lds((const AS1 void*)s1, (AS3 void*)(d + c1 * 8), 16, 0, 0);
    };
    auto stageB = [&](int t, int h) {
        const bf16_t* s0 = Bb + (long)(h * 128 + r0) * K + t * 64 + cb0 * 8;
        const bf16_t* s1 = Bb + (long)(h * 128 + r1) * K + t * 64 + cb1 * 8;
        bf16_t* d = lds + 32768 + ((t & 1) * 2 + h) * 8192;
        __builtin_amdgcn_global_load_lds((const AS1 void*)s0, (AS3 void*)(d + c0 * 8), 16, 0, 0);
        __builtin_amdgcn_global_load_lds((const AS1 void*)s1, (AS3 void*)(d + c1 * 8), 16, 0, 0);
    };
    auto ldA = [&](int t, int mf, int kk) -> bf16x8 {
        const int row = mf * 16 + lrow;
        const int col = (kk * 32 + kgrp * 8) ^ ((row & 7) << 3);
        return *(const bf16x8*)(lds + ((t & 1) * 2 + wm) * 8192 + row * 64 + col);
    };
    auto ldB = [&](int t, int g, int kk) -> bf16x8 {
        const int row = (wn & 1) * 64 + lrow * 4 + g;
        const int col = (kk * 32 + kgrp * 8) ^ (((row >> 2) & 7) << 3);
        return *(const bf16x8*)(lds + 32768 + ((t & 1) * 2 + (wn >> 1)) * 8192 + row * 64 + col);
    };

    f32x4 acc[8][4] = {};
    bf16x8 bfr[4][2];

    stageA(0, 0); stageA(0, 1); stageB(0, 0); stageB(0, 1); stageB(1, 0); stageB(1, 1);
    asm volatile("s_waitcnt vmcnt(4)" ::: "memory");
    __builtin_amdgcn_s_barrier();

#pragma unroll
    for (int i = 0; i < 2; ++i) {
#pragma unroll
        for (int p = 0; p < 8; ++p) {
            const int q = p & 3;
            const int t = 2 * i + (p >> 2);
            bf16x8 af[2][2];
            if (q == 0) {
#pragma unroll
                for (int g = 0; g < 4; ++g) { bfr[g][0] = ldB(t, g, 0); bfr[g][1] = ldB(t, g, 1); }
            }
#pragma unroll
            for (int mm = 0; mm < 2; ++mm) { af[mm][0] = ldA(t, 2 * q + mm, 0); af[mm][1] = ldA(t, 2 * q + mm, 1); }

            if (p == 0) stageA(2 * i + 1, 0);
            else if (p == 1) stageA(2 * i + 1, 1);
            else if (p == 2) { if (2 * i + 2 < 4) stageB(2 * i + 2, 0); }
            else if (p == 3) { if (2 * i + 2 < 4) stageB(2 * i + 2, 1); }
            else if (p == 4) { if (2 * i + 2 < 4) stageA(2 * i + 2, 0); }
            else if (p == 5) { if (2 * i + 2 < 4) stageA(2 * i + 2, 1); }
            else if (p == 6) { if (2 * i + 3 < 4) stageB(2 * i + 3, 0); }
            else             { if (2 * i + 3 < 4) stageB(2 * i + 3, 1); }

            __builtin_amdgcn_s_barrier();
            asm volatile("s_waitcnt lgkmcnt(0)" ::: "memory");
            __builtin_amdgcn_s_setprio(1);
#pragma unroll
            for (int mm = 0; mm < 2; ++mm)
#pragma unroll
                for (int g = 0; g < 4; ++g)
#pragma unroll
                    for (int kk = 0; kk < 2; ++kk)
                        acc[2 * q + mm][g] = __builtin_amdgcn_mfma_f32_16x16x32_bf16(
                            af[mm][kk], bfr[g][kk], acc[2 * q + mm][g], 0, 0, 0);
            __builtin_amdgcn_s_setprio(0);

            if (p == 3) {
                if (2 * i + 2 < 4) asm volatile("s_waitcnt vmcnt(4)" ::: "memory");
                else               asm volatile("s_waitcnt vmcnt(0)" ::: "memory");
            } else if (p == 7) {
                if (2 * i + 2 < 4) asm volatile("s_waitcnt vmcnt(4)" ::: "memory");
            }
            __builtin_amdgcn_s_barrier();
        }
    }

    const long rb = (long)mblk * 256 + wm * 128 + kgrp * 4;
    const long cb = (long)nblk * 256 + wn * 64 + lrow * 4;
    if constexpr (EPI == 0) {
        float* C = (float*)Cv + (long)bz * sC;
#pragma unroll
        for (int m = 0; m < 8; ++m)
#pragma unroll
            for (int j = 0; j < 4; ++j) {
                f32x4 v = { acc[m][0][j], acc[m][1][j], acc[m][2][j], acc[m][3][j] };
                __builtin_nontemporal_store(v, (f32x4*)(C + (rb + m * 16 + j) * N + cb));
            }
    } else {
        bf16_t* C = (bf16_t*)Cv;
        f32x4 bv = *(const f32x4*)(bias + (int)(cb & 255));
#pragma unroll
        for (int m = 0; m < 8; ++m)
#pragma unroll
            for (int j = 0; j < 4; ++j) {
                bf16x4 v;
#pragma unroll
                for (int g = 0; g < 4; ++g) v[g] = (bf16_t)(acc[m][g][j] + bv[g]);
                *(bf16x4*)(C + (rb + m * 16 + j) * N + cb) = v;
            }
    }
}

// ---------------------------------------------------------------------------
// GEMM3 (R6 form — best measured): out_b = bl_b[12288,256] @ t_b[1024,256]^T,
// fp32 NT out. 192x128 tile, BK=64 dbuf, 256 threads, 80 KB LDS -> 2
// blocks/CU; stage(t+1) -> ds_read(t) -> 48 MFMA -> __syncthreads.
// Write-bound: 402 MB fp32 at ~4.9 TB/s effective (mixed-stream ceiling).
// ---------------------------------------------------------------------------
template <int NNB>
__global__ __launch_bounds__(256, 2)
void gemm3k(const bf16_t* __restrict__ A, const bf16_t* __restrict__ Bm,
            float* __restrict__ C, long sA, long sB, long sC) {
    constexpr int K = 256, BM = 192, BN = 128;
    extern __shared__ bf16_t lds[];   // A: buf*12288 ; B: 24576 + buf*8192

    const int tid  = threadIdx.x;
    const int lane = tid & 63;
    const int wave = tid >> 6;
    const int wm = wave >> 1, wn = wave & 1;
    const int lrow = lane & 15, kgrp = lane >> 4;

    const int L = blockIdx.x;
    const int bz = L & 7;
    const int w = L >> 3;
    const int nblk = w & (NNB - 1), mblk = w / NNB;

    const bf16_t* Ab = A + (long)bz * sA + (long)mblk * BM * K;
    const bf16_t* Bb = Bm + (long)bz * sB + (long)nblk * BN * K;

    auto stage = [&](int t) {
        const int buf = t & 1;
#pragma unroll
        for (int it = 0; it < 6; ++it) {          // A: 192x64 = 1536 chunks
            const int c = it * 256 + tid, row = c >> 3;
            const int sa = (c & 7) ^ (row & 7);
            __builtin_amdgcn_global_load_lds(
                (const AS1 void*)(Ab + (long)row * K + t * 64 + sa * 8),
                (AS3 void*)(lds + buf * 12288 + c * 8), 16, 0, 0);
        }
#pragma unroll
        for (int it = 0; it < 4; ++it) {          // B: 128x64 = 1024 chunks
            const int c = it * 256 + tid, row = c >> 3;
            const int sb = (c & 7) ^ ((row >> 2) & 7);
            __builtin_amdgcn_global_load_lds(
                (const AS1 void*)(Bb + (long)row * K + t * 64 + sb * 8),
                (AS3 void*)(lds + 24576 + buf * 8192 + c * 8), 16, 0, 0);
        }
    };

    f32x4 acc[6][4] = {};

    stage(0);
    __syncthreads();

#pragma unroll
    for (int t = 0; t < 4; ++t) {
        if (t < 3) stage(t + 1);
        const int buf = t & 1;
        bf16x8 af[6][2], bfr[4][2];
#pragma unroll
        for (int m = 0; m < 6; ++m) {
            const int r = wm * 96 + m * 16 + lrow;
#pragma unroll
            for (int kk = 0; kk < 2; ++kk)
                af[m][kk] = *(const bf16x8*)(lds + buf * 12288 + r * 64 +
                                             ((kk * 32 + kgrp * 8) ^ ((r & 7) << 3)));
        }
#pragma unroll
        for (int g = 0; g < 4; ++g) {
            const int r = wn * 64 + lrow * 4 + g;
#pragma unroll
            for (int kk = 0; kk < 2; ++kk)
                bfr[g][kk] = *(const bf16x8*)(lds + 24576 + buf * 8192 + r * 64 +
                                              ((kk * 32 + kgrp * 8) ^ (((r >> 2) & 7) << 3)));
        }
        __builtin_amdgcn_s_setprio(1);
#pragma unroll
        for (int m = 0; m < 6; ++m)
#pragma unroll
            for (int g = 0; g < 4; ++g)
#pragma unroll
                for (int kk = 0; kk < 2; ++kk)
                    acc[m][g] = __builtin_amdgcn_mfma_f32_16x16x32_bf16(
                        af[m][kk], bfr[g][kk], acc[m][g], 0, 0, 0);
        __builtin_amdgcn_s_setprio(0);
        __syncthreads();
    }

    float* Cb = C + (long)bz * sC;
    const long rb = (long)mblk * BM + wm * 96 + kgrp * 4;
    const long cb = (long)nblk * BN + wn * 64 + lrow * 4;
#pragma unroll
    for (int m = 0; m < 6; ++m)
#pragma unroll
        for (int j = 0; j < 4; ++j) {
            f32x4 v = { acc[m][0][j], acc[m][1][j], acc[m][2][j], acc[m][3][j] };
            __builtin_nontemporal_store(v, (f32x4*)(Cb + (rb + m * 16 + j) * 1024 + cb));
        }
}

// ---------------------------------------------------------------------------
// B=8, S=1024, IN=768, E=256, L=12. 3 dispatches total.
// ---------------------------------------------------------------------------
extern "C" void kernel_launch(void* const* d_in, const int* in_sizes, int n_in,
                              void* d_out, int out_size, void* d_ws, size_t ws_size,
                              hipStream_t stream) {
    const float* input = (const float*)d_in[0];
    const float* fc_w  = (const float*)d_in[1];
    const float* fc_b  = (const float*)d_in[2];
    const float* bi_w  = (const float*)d_in[3];
    // bias (d_in[4]) is all-zeros in setup; still honored via gemm8p epilogue
    const float* bias  = (const float*)d_in[4];

    char* ws = (char*)d_ws;
    bf16_t* wbi = (bf16_t*)(ws);             // 3072*256*2 = 1,572,864
    bf16_t* t   = (bf16_t*)(ws + 1572864);   // 8192*256*2 = 4,194,304
    bf16_t* bl  = (bf16_t*)(ws + 5767168);   // 8192*3072*2 = 50,331,648

    // Front-end: bi_w cvt (384 blocks) + GEMM1 w/ fused A,B cvt (256 blocks)
    frontend<<<dim3(640), dim3(256), 0, stream>>>(
        input, fc_w, fc_b, bi_w, wbi, t);

    // GEMM2: bl = t @ wbi^T + bias[col&255]  (8-phase 256^2; 384 blocks)
    gemm8p<2, 0, 32, 12><<<dim3(384), dim3(512), 131072, stream>>>(
        t, wbi, (void*)bl, bias, 3072, 0L, 0L, 0L);

    // GEMM3 (batched x8): 192x128 tile, 4096 blocks, 2/CU, NT stores
    gemm3k<8><<<dim3(4096), dim3(256), 81920, stream>>>(
        bl, t, (float*)d_out,
        (long)12288 * 256, (long)1024 * 256, (long)12288 * 1024);
}